// Round 13
// baseline (12983.038 us; speedup 1.0000x reference)
//
#include <hip/hip_runtime.h>

typedef __attribute__((ext_vector_type(8))) short bf16x8;
typedef __attribute__((ext_vector_type(4))) float f32x4;
typedef __attribute__((ext_vector_type(4))) unsigned int u32x4;

#define T_SEQ 2048
#define RING  64
#define LWG   16   // WGs per LSTM layer (512 threads each)
#define FWG   4    // FC WGs (512 threads each)
#define NWG   (LWG + LWG + FWG)
#define SLOT_STRIDE 16  // ints; 64B per slot
#define NEG_INF (-1000000)

// XOR swizzle for 1024B-row-stride LDS tiles (spreads 8 rows over 8 16B slots)
#define HSWZ(o) ((o) ^ ((((o) >> 10) & 7) << 4))

static __device__ __forceinline__ unsigned short f2b(float f) {
  unsigned u = __float_as_uint(f);
  u = (u + 0x7fffu + ((u >> 16) & 1u)) >> 16;
  return (unsigned short)u;
}
static __device__ __forceinline__ float sigm(float x) { return 1.f / (1.f + __expf(-x)); }
static __device__ __forceinline__ float tanh_f(float x) { return 2.f / (1.f + __expf(-2.f * x)) - 1.f; }

// ---- LLC-coherent (cross-XCD) bulk data movement (round-2/5-proven) ----
static __device__ __forceinline__ u32x4 llc_load16(const void* p) {
  u32x4 v;
  asm volatile("global_load_dwordx4 %0, %1, off sc0 sc1" : "=v"(v) : "v"(p) : "memory");
  return v;
}
static __device__ __forceinline__ void llc_store4(void* p, unsigned v) {
  asm volatile("global_store_dword %0, %1, off sc0 sc1" :: "v"(p), "v"(v) : "memory");
}
static __device__ __forceinline__ void vmwait() {
  asm volatile("s_waitcnt vmcnt(0)" ::: "memory");
}
// flag ops: compiler-generated relaxed system-scope atomics (round-5-proven)
static __device__ __forceinline__ int flag_ld(const int* p) {
  return __hip_atomic_load(p, __ATOMIC_RELAXED, __HIP_MEMORY_SCOPE_SYSTEM);
}
static __device__ __forceinline__ void flag_st(int* p, int v) {
  __hip_atomic_store(p, v, __ATOMIC_RELAXED, __HIP_MEMORY_SCOPE_SYSTEM);
}

// wave-0-only poll: lanes 0-15 check s0[lane]>=n0, lanes 32-47 check
// s1[lane-32]>=n1, lanes 0-3 additionally sf[lane]>=nf. NEG_INF disables.
static __device__ void spin_flags(const int* s0, int n0, const int* s1, int n1,
                                  const int* sf, int nf) {
  if (threadIdx.x < 64) {
    const int lane = threadIdx.x;
    const bool g1 = (lane < 16) && (n0 > NEG_INF);
    const bool g2 = (lane >= 32) && (lane < 48) && (n1 > NEG_INF);
    const int* p1 = g1 ? (s0 + lane * SLOT_STRIDE)
                       : (g2 ? (s1 + (lane - 32) * SLOT_STRIDE) : s0);
    const int need1 = g1 ? n0 : n1;
    const int* p2 = sf + (lane & 3) * SLOT_STRIDE;
    const bool chk2 = (lane < 4) && (nf > NEG_INF);
    for (;;) {
      int v1 = (g1 || g2) ? flag_ld(p1) : 0x7fffffff;
      int v2 = chk2 ? flag_ld(p2) : 0x7fffffff;
      int ok = (!(g1 || g2) || (v1 >= need1)) && (!chk2 || (v2 >= nf));
      if (__all(ok)) break;
    }
  }
  __syncthreads();
}

// ---------------- prologue: pack weights bf16, transpose x, zero state ----------------
__global__ void lstm_prologue(
    const float* __restrict__ x, const float* __restrict__ wih0, const float* __restrict__ whh0,
    const float* __restrict__ wih1, const float* __restrict__ whh1, const float* __restrict__ wfc,
    unsigned short* __restrict__ wl0, unsigned short* __restrict__ wl1,
    unsigned short* __restrict__ wfcp, unsigned short* __restrict__ xb,
    unsigned short* __restrict__ h0r, unsigned short* __restrict__ h1r,
    int* __restrict__ flags) {
  size_t tid = (size_t)blockIdx.x * blockDim.x + threadIdx.x;
  size_t nthr = (size_t)gridDim.x * blockDim.x;
  for (size_t i = tid; i < (size_t)2048 * 768; i += nthr) {
    int r = (int)(i / 768), k = (int)(i % 768);
    float v = (k < 256) ? wih0[(size_t)r * 256 + k] : whh0[(size_t)r * 512 + (k - 256)];
    wl0[i] = f2b(v);
  }
  for (size_t i = tid; i < (size_t)2048 * 1024; i += nthr) {
    int r = (int)(i >> 10), k = (int)(i & 1023);
    float v = (k < 512) ? wih1[((size_t)r << 9) + k] : whh1[((size_t)r << 9) + (k - 512)];
    wl1[i] = f2b(v);
  }
  for (size_t i = tid; i < 131072; i += nthr) wfcp[i] = f2b(wfc[i]);
  // xb: [T][B][256] bf16 from x [B][T][256] f32
  for (size_t i = tid; i < (size_t)16777216; i += nthr) {
    int ii = (int)(i & 255), b = (int)((i >> 8) & 31), t = (int)(i >> 13);
    xb[i] = f2b(x[((size_t)b * 2048 + t) * 256 + ii]);
  }
  for (size_t i = tid; i < (size_t)NWG * SLOT_STRIDE; i += nthr) flags[i] = 0;
  for (size_t i = tid; i < 32 * 512; i += nthr) {
    h0r[(size_t)(RING - 1) * 32 * 512 + i] = 0;
    h1r[(size_t)(RING - 1) * 32 * 512 + i] = 0;
  }
}

// ---------------- LSTM layer workgroup body (512 thr, 8 waves, 32 units) ----------------
// wave w: gate (w&3), unit half (w>>2) -> rows (w&3)*512 + u0 + (w>>2)*16 + l15
template <int ISL0>
static __device__ void lstm_path(
    const unsigned short* __restrict__ xb, const unsigned short* __restrict__ wl,
    const float* __restrict__ bias,
    unsigned short* __restrict__ h0r, unsigned short* __restrict__ h1r,
    int* s0, int* s1, int* sf, int wid2,
    unsigned short* hA, unsigned short* xA, float (*gates)[32][18]) {
  const int tid = threadIdx.x;
  const int wave = tid >> 6, lane = tid & 63, l15 = lane & 15, kgrp = lane >> 4;
  const int u0 = wid2 * 32;
  constexpr int K = ISL0 ? 768 : 1024;
  constexpr int NKW = ISL0 ? 24 : 32;
  const int grow = (wave & 3) * 512 + u0 + ((wave >> 2) << 4);
  const unsigned short* wrow = wl + (size_t)(grow + l15) * K;

  // weight-stationary fragments: 512-thr/launch_bounds(512,1) -> 256-VGPR
  // budget -> these fit resident; pin against rematerialization.
  bf16x8 wf[NKW];
#pragma unroll
  for (int kk = 0; kk < NKW; ++kk) {
    wf[kk] = *(const bf16x8*)(wrow + kk * 32 + kgrp * 8);
    asm volatile("" : "+v"(wf[kk]));
  }

  const int ue = 2 * (tid & 15);   // unit pair within the WG's 32 units
  const int be = tid >> 4;         // batch
  const float bi0 = bias[0 * 512 + u0 + ue], bi1 = bias[0 * 512 + u0 + ue + 1];
  const float bf0 = bias[1 * 512 + u0 + ue], bf1 = bias[1 * 512 + u0 + ue + 1];
  const float bg0 = bias[2 * 512 + u0 + ue], bg1 = bias[2 * 512 + u0 + ue + 1];
  const float bo0 = bias[3 * 512 + u0 + ue], bo1 = bias[3 * 512 + u0 + ue + 1];
  float cc0 = 0.f, cc1 = 0.f;
  unsigned short* myring = ISL0 ? h0r : h1r;
  int* myslot = (ISL0 ? s0 : s1) + wid2 * SLOT_STRIDE;

  for (int t = 0; t < T_SEQ; ++t) {
    f32x4 acc0 = {0.f, 0.f, 0.f, 0.f}, acc1 = {0.f, 0.f, 0.f, 0.f};

    if (ISL0) {
      // x fragment prefetch (static data, issued before the poll)
      bf16x8 xf0[8], xf1[8];
      const unsigned short* xt = xb + (size_t)t * (32 * 256);
#pragma unroll
      for (int kk = 0; kk < 8; ++kk) {
        xf0[kk] = *(const bf16x8*)(xt + l15 * 256 + kk * 32 + kgrp * 8);
        xf1[kk] = *(const bf16x8*)(xt + (16 + l15) * 256 + kk * 32 + kgrp * 8);
      }
      // the real wait: peers' h0[t-1]; L1 progress = ring guard
      spin_flags(s0, t, s1, t - (RING - 1), sf, NEG_INF);

      // stage h0[t-1] (4 x 16B chunks/thread); x-part MFMAs overlap the loads
      const unsigned short* hprev = myring + (size_t)((t - 1) & (RING - 1)) * (32 * 512);
      u32x4 th[4];
#pragma unroll
      for (int k = 0; k < 4; ++k)
        th[k] = llc_load16((const char*)hprev + (size_t)(tid + k * 512) * 16);
#pragma unroll
      for (int kk = 0; kk < 8; ++kk) {
        acc0 = __builtin_amdgcn_mfma_f32_16x16x32_bf16(xf0[kk], wf[kk], acc0, 0, 0, 0);
        acc1 = __builtin_amdgcn_mfma_f32_16x16x32_bf16(xf1[kk], wf[kk], acc1, 0, 0, 0);
      }
      vmwait();
#pragma unroll
      for (int k = 0; k < 4; ++k) {
        int off = (tid + k * 512) * 16;
        *(u32x4*)((char*)hA + HSWZ(off)) = th[k];
      }
      __syncthreads();
#pragma unroll
      for (int kk = 0; kk < 16; ++kk) {
        int cb = (kk * 32 + kgrp * 8) * 2;
        bf16x8 a0 = *(const bf16x8*)((const char*)hA + HSWZ(l15 * 1024 + cb));
        bf16x8 a1 = *(const bf16x8*)((const char*)hA + HSWZ((16 + l15) * 1024 + cb));
        acc0 = __builtin_amdgcn_mfma_f32_16x16x32_bf16(a0, wf[8 + kk], acc0, 0, 0, 0);
        acc1 = __builtin_amdgcn_mfma_f32_16x16x32_bf16(a1, wf[8 + kk], acc1, 0, 0, 0);
      }
    } else {
      // ---- pre-poll phase: everything touching h0[t] (L0 runs ahead) ----
      spin_flags(s0, t + 1, s1, NEG_INF, sf, NEG_INF);
      const unsigned short* h0cur = h0r + (size_t)(t & (RING - 1)) * (32 * 512);
      u32x4 tx[4];
#pragma unroll
      for (int k = 0; k < 4; ++k)
        tx[k] = llc_load16((const char*)h0cur + (size_t)(tid + k * 512) * 16);
      vmwait();
#pragma unroll
      for (int k = 0; k < 4; ++k) {
        int off = (tid + k * 512) * 16;
        *(u32x4*)((char*)xA + HSWZ(off)) = tx[k];
      }
      __syncthreads();  // xA published
#pragma unroll
      for (int kk = 0; kk < 16; ++kk) {
        int cb = (kk * 32 + kgrp * 8) * 2;
        bf16x8 a0 = *(const bf16x8*)((const char*)xA + HSWZ(l15 * 1024 + cb));
        bf16x8 a1 = *(const bf16x8*)((const char*)xA + HSWZ((16 + l15) * 1024 + cb));
        acc0 = __builtin_amdgcn_mfma_f32_16x16x32_bf16(a0, wf[kk], acc0, 0, 0, 0);
        acc1 = __builtin_amdgcn_mfma_f32_16x16x32_bf16(a1, wf[kk], acc1, 0, 0, 0);
      }

      // ---- critical phase: peers' h1[t-1] (+ FC ring guard) ----
      spin_flags(s0, NEG_INF, s1, t, sf, t - (RING - 1));
      const unsigned short* hprev = myring + (size_t)((t - 1) & (RING - 1)) * (32 * 512);
      u32x4 th[4];
#pragma unroll
      for (int k = 0; k < 4; ++k)
        th[k] = llc_load16((const char*)hprev + (size_t)(tid + k * 512) * 16);
      vmwait();
#pragma unroll
      for (int k = 0; k < 4; ++k) {
        int off = (tid + k * 512) * 16;
        *(u32x4*)((char*)hA + HSWZ(off)) = th[k];
      }
      __syncthreads();
#pragma unroll
      for (int kk = 0; kk < 16; ++kk) {
        int cb = (kk * 32 + kgrp * 8) * 2;
        bf16x8 a0 = *(const bf16x8*)((const char*)hA + HSWZ(l15 * 1024 + cb));
        bf16x8 a1 = *(const bf16x8*)((const char*)hA + HSWZ((16 + l15) * 1024 + cb));
        acc0 = __builtin_amdgcn_mfma_f32_16x16x32_bf16(a0, wf[16 + kk], acc0, 0, 0, 0);
        acc1 = __builtin_amdgcn_mfma_f32_16x16x32_bf16(a1, wf[16 + kk], acc1, 0, 0, 0);
      }
    }

    // C/D: col(l15)=unit-in-tile, row(kgrp*4+j)=batch.  gates[wave][batch][unit16]
#pragma unroll
    for (int j = 0; j < 4; ++j) {
      gates[wave][kgrp * 4 + j][l15] = acc0[j];
      gates[wave][16 + kgrp * 4 + j][l15] = acc1[j];
    }
    __syncthreads();

    // ---- epilogue: 2 units x 1 batch per thread; c stays in registers ----
    unsigned short* hdst = myring + (size_t)(t & (RING - 1)) * (32 * 512);
    const int wb = (ue >> 4) << 2;  // wave block for this unit half
    const int ul = ue & 15;
    float i0 = sigm(gates[0 + wb][be][ul] + bi0);
    float ff0 = sigm(gates[1 + wb][be][ul] + bf0);
    float g0 = tanh_f(gates[2 + wb][be][ul] + bg0);
    float o0 = sigm(gates[3 + wb][be][ul] + bo0);
    cc0 = ff0 * cc0 + i0 * g0;
    float hv0 = o0 * tanh_f(cc0);
    float i1 = sigm(gates[0 + wb][be][ul + 1] + bi1);
    float ff1 = sigm(gates[1 + wb][be][ul + 1] + bf1);
    float g1 = tanh_f(gates[2 + wb][be][ul + 1] + bg1);
    float o1 = sigm(gates[3 + wb][be][ul + 1] + bo1);
    cc1 = ff1 * cc1 + i1 * g1;
    float hv1 = o1 * tanh_f(cc1);
    unsigned pv = (unsigned)f2b(hv0) | ((unsigned)f2b(hv1) << 16);
    llc_store4(hdst + (size_t)be * 512 + u0 + ue, pv);
    vmwait();            // drain BEFORE flag (r11 lesson)
    __syncthreads();
    if (tid == 0) flag_st(myslot, t + 1);
  }
}

// ---------------- main kernel: 36 WGs x 512 threads ----------------
__global__ void __launch_bounds__(512, 1) lstm_main(
    const unsigned short* __restrict__ xb,
    const unsigned short* __restrict__ wl0,
    const unsigned short* __restrict__ wl1,
    const unsigned short* __restrict__ wfcp,
    const float* __restrict__ b0,
    const float* __restrict__ b1,
    const float* __restrict__ bfc,
    unsigned short* __restrict__ h0r,
    unsigned short* __restrict__ h1r,
    int* flags,
    float* __restrict__ out) {
  __shared__ __align__(16) unsigned short hA[32 * 512];
  __shared__ __align__(16) unsigned short xA[32 * 512];
  __shared__ __align__(16) float gates[8][32][18];
  const int tid = threadIdx.x;
  const int wave = tid >> 6, lane = tid & 63, l15 = lane & 15, kgrp = lane >> 4;
  const int wid = blockIdx.x;
  int* s0 = flags;
  int* s1 = flags + LWG * SLOT_STRIDE;
  int* sf = flags + 2 * LWG * SLOT_STRIDE;

  if (wid < LWG) {
    lstm_path<1>(xb, wl0, b0, h0r, h1r, s0, s1, sf, wid, hA, xA, gates);
  } else if (wid < 2 * LWG) {
    lstm_path<0>(xb, wl1, b1, h0r, h1r, s0, s1, sf, wid - LWG, hA, xA, gates);
  } else {
    const int fcw = wid - 2 * LWG;  // 0..3, each owns 64 output rows
    const int mt = wave >> 2, rtile = wave & 3;
    const int orow = fcw * 64 + rtile * 16 + l15;
    bf16x8 wff[16];
#pragma unroll
    for (int kk = 0; kk < 16; ++kk) {
      wff[kk] = *(const bf16x8*)(wfcp + (size_t)orow * 512 + kk * 32 + kgrp * 8);
      asm volatile("" : "+v"(wff[kk]));
    }
    const float bb = bfc[orow];
    for (int t = 0; t < T_SEQ; ++t) {
      spin_flags(s0, NEG_INF, s1, t + 1, sf, NEG_INF);
      const unsigned short* hcur = h1r + (size_t)(t & (RING - 1)) * (32 * 512);
      unsigned short* buf = (t & 1) ? xA : hA;  // double buffer: safe LDS reuse
      u32x4 th[4];
#pragma unroll
      for (int k = 0; k < 4; ++k)
        th[k] = llc_load16((const char*)hcur + (size_t)(tid + k * 512) * 16);
      vmwait();
#pragma unroll
      for (int k = 0; k < 4; ++k) {
        int off = (tid + k * 512) * 16;
        *(u32x4*)((char*)buf + HSWZ(off)) = th[k];
      }
      __syncthreads();
      if (tid == 0) flag_st(sf + fcw * SLOT_STRIDE, t + 1);  // h1[t] consumed
      f32x4 acc = {0.f, 0.f, 0.f, 0.f};
#pragma unroll
      for (int kk = 0; kk < 16; ++kk) {
        int row = mt * 16 + l15;
        bf16x8 a = *(const bf16x8*)((const char*)buf + HSWZ(row * 1024 + (kk * 32 + kgrp * 8) * 2));
        acc = __builtin_amdgcn_mfma_f32_16x16x32_bf16(a, wff[kk], acc, 0, 0, 0);
      }
#pragma unroll
      for (int j = 0; j < 4; ++j) {
        int b = mt * 16 + kgrp * 4 + j;
        out[((size_t)b * T_SEQ + t) * 256 + orow] = acc[j] + bb;
      }
    }
  }
}

extern "C" void kernel_launch(void* const* d_in, const int* in_sizes, int n_in,
                              void* d_out, int out_size, void* d_ws, size_t ws_size,
                              hipStream_t stream) {
  const float* x    = (const float*)d_in[0];
  const float* wih0 = (const float*)d_in[1];
  const float* whh0 = (const float*)d_in[2];
  const float* b0   = (const float*)d_in[3];
  const float* wih1 = (const float*)d_in[4];
  const float* whh1 = (const float*)d_in[5];
  const float* b1   = (const float*)d_in[6];
  const float* wfc  = (const float*)d_in[7];
  const float* bfc  = (const float*)d_in[8];
  float* outp = (float*)d_out;

  char* ws = (char*)d_ws;
  size_t off = 0;
  unsigned short* wl0p = (unsigned short*)(ws + off); off += (size_t)2048 * 768 * 2;
  unsigned short* wl1p = (unsigned short*)(ws + off); off += (size_t)2048 * 1024 * 2;
  unsigned short* wfcp = (unsigned short*)(ws + off); off += (size_t)256 * 512 * 2;
  unsigned short* xbp  = (unsigned short*)(ws + off); off += (size_t)2048 * 32 * 256 * 2;
  unsigned short* h0rp = (unsigned short*)(ws + off); off += (size_t)RING * 32 * 512 * 2;
  unsigned short* h1rp = (unsigned short*)(ws + off); off += (size_t)RING * 32 * 512 * 2;
  int* flagsp = (int*)(ws + off); off += (size_t)NWG * SLOT_STRIDE * sizeof(int);

  lstm_prologue<<<dim3(1024), dim3(256), 0, stream>>>(
      x, wih0, whh0, wih1, whh1, wfc, wl0p, wl1p, wfcp, xbp, h0rp, h1rp, flagsp);

  lstm_main<<<dim3(NWG), dim3(512), 0, stream>>>(
      xbp, wl0p, wl1p, wfcp, b0, b1, bfc, h0rp, h1rp, flagsp, outp);
}

// Round 14
// 11117.093 us; speedup vs baseline: 1.1678x; 1.1678x over previous
//
#include <hip/hip_runtime.h>

typedef __attribute__((ext_vector_type(8))) short bf16x8;
typedef __attribute__((ext_vector_type(4))) float f32x4;
typedef __attribute__((ext_vector_type(4))) unsigned int u32x4;

#define T_SEQ 2048
#define RING  64
#define NL0   32
#define NL1   32
#define NFC   8
#define NWG   (NL0 + NL1 + NFC)
#define SLOT_STRIDE 16  // ints; 64B per slot
#define NEG_INF (-1000000)

// XOR swizzle for 1024B-row-stride LDS tiles (spreads 8 rows over 8 16B slots)
#define HSWZ(o) ((o) ^ ((((o) >> 10) & 7) << 4))

static __device__ __forceinline__ unsigned short f2b(float f) {
  unsigned u = __float_as_uint(f);
  u = (u + 0x7fffu + ((u >> 16) & 1u)) >> 16;
  return (unsigned short)u;
}
static __device__ __forceinline__ float sigm(float x) { return 1.f / (1.f + __expf(-x)); }
static __device__ __forceinline__ float tanh_f(float x) { return 2.f / (1.f + __expf(-2.f * x)) - 1.f; }

// ---- LLC-coherent (cross-XCD) bulk data movement (round-2/5-proven) ----
static __device__ __forceinline__ u32x4 llc_load16(const void* p) {
  u32x4 v;
  asm volatile("global_load_dwordx4 %0, %1, off sc0 sc1" : "=v"(v) : "v"(p) : "memory");
  return v;
}
static __device__ __forceinline__ void llc_store4(void* p, unsigned v) {
  asm volatile("global_store_dword %0, %1, off sc0 sc1" :: "v"(p), "v"(v) : "memory");
}
static __device__ __forceinline__ void vmwait() {
  asm volatile("s_waitcnt vmcnt(0)" ::: "memory");
}
// flag ops: compiler-generated relaxed system-scope atomics (round-5-proven)
static __device__ __forceinline__ int flag_ld(const int* p) {
  return __hip_atomic_load(p, __ATOMIC_RELAXED, __HIP_MEMORY_SCOPE_SYSTEM);
}
static __device__ __forceinline__ void flag_st(int* p, int v) {
  __hip_atomic_store(p, v, __ATOMIC_RELAXED, __HIP_MEMORY_SCOPE_SYSTEM);
}

// round-5-proven wave-parallel poll: lanes 0-31 check s0>=n0, 32-63 check
// s1>=n1, lanes 0-7 additionally sf>=nf. NEG_INF disables a group.
static __device__ void spin_flags(const int* s0, int n0, const int* s1, int n1,
                                  const int* sf, int nf) {
  if (threadIdx.x < 64) {
    const int lane = threadIdx.x;
    const int* p1 = (lane < 32) ? (s0 + lane * SLOT_STRIDE) : (s1 + (lane - 32) * SLOT_STRIDE);
    const int need1 = (lane < 32) ? n0 : n1;
    const int* p2 = sf + (lane & 7) * SLOT_STRIDE;
    const bool chk2 = (lane < 8) && (nf > NEG_INF);
    for (;;) {
      int v1 = flag_ld(p1);
      int v2 = chk2 ? flag_ld(p2) : 0x7fffffff;
      int ok = (v1 >= need1) && (!chk2 || (v2 >= nf));
      if (__all(ok)) break;
    }
  }
  __syncthreads();
}

// ---------------- prologue: pack weights bf16, transpose x, zero state ----------------
__global__ void lstm_prologue(
    const float* __restrict__ x, const float* __restrict__ wih0, const float* __restrict__ whh0,
    const float* __restrict__ wih1, const float* __restrict__ whh1, const float* __restrict__ wfc,
    unsigned short* __restrict__ wl0, unsigned short* __restrict__ wl1,
    unsigned short* __restrict__ wfcp, unsigned short* __restrict__ xb,
    unsigned short* __restrict__ h0r, unsigned short* __restrict__ h1r,
    int* __restrict__ flags) {
  size_t tid = (size_t)blockIdx.x * blockDim.x + threadIdx.x;
  size_t nthr = (size_t)gridDim.x * blockDim.x;
  for (size_t i = tid; i < (size_t)2048 * 768; i += nthr) {
    int r = (int)(i / 768), k = (int)(i % 768);
    float v = (k < 256) ? wih0[(size_t)r * 256 + k] : whh0[(size_t)r * 512 + (k - 256)];
    wl0[i] = f2b(v);
  }
  for (size_t i = tid; i < (size_t)2048 * 1024; i += nthr) {
    int r = (int)(i >> 10), k = (int)(i & 1023);
    float v = (k < 512) ? wih1[((size_t)r << 9) + k] : whh1[((size_t)r << 9) + (k - 512)];
    wl1[i] = f2b(v);
  }
  for (size_t i = tid; i < 131072; i += nthr) wfcp[i] = f2b(wfc[i]);
  // xb: [T][B][256] bf16 from x [B][T][256] f32
  for (size_t i = tid; i < (size_t)16777216; i += nthr) {
    int ii = (int)(i & 255), b = (int)((i >> 8) & 31), t = (int)(i >> 13);
    xb[i] = f2b(x[((size_t)b * 2048 + t) * 256 + ii]);
  }
  for (size_t i = tid; i < (size_t)NWG * SLOT_STRIDE; i += nthr) flags[i] = 0;
  for (size_t i = tid; i < 32 * 512; i += nthr) {
    h0r[(size_t)(RING - 1) * 32 * 512 + i] = 0;
    h1r[(size_t)(RING - 1) * 32 * 512 + i] = 0;
  }
}

// ---------------- LSTM layer workgroup body ----------------
// Critical-path (w_hh) weights live in LDS (wB, 64 rows x 512 K, swizzled) —
// register residency failed 4x (compiler rematerializes); LDS is deterministic.
template <int ISL0>
static __device__ void lstm_path(
    const unsigned short* __restrict__ xb, const unsigned short* __restrict__ wl,
    const float* __restrict__ bias,
    unsigned short* __restrict__ h0r, unsigned short* __restrict__ h1r,
    int* s0, int* s1, int* sf, int wid2,
    unsigned short* hA, unsigned short* xA, unsigned short* wB,
    float (*gates)[32][18]) {
  const int tid = threadIdx.x;
  const int wave = tid >> 6, lane = tid & 63, l15 = lane & 15, kgrp = lane >> 4;
  const int u0 = wid2 * 16;
  constexpr int K = ISL0 ? 768 : 1024;
  constexpr int KOFF = ISL0 ? 256 : 512;  // k-offset of the w_hh part

  // ---- stage recurrent weight slice into LDS: rows r = gate*16+unit ----
  for (int c = tid; c < 4096; c += 256) {  // 4096 x 16B chunks = 64 KB
    int off = c * 16;
    int r = off >> 10;
    int kb = off & 1023;
    int grow = (r >> 4) * 512 + u0 + (r & 15);
    u32x4 v = *(const u32x4*)(wl + (size_t)grow * K + KOFF + (kb >> 1));
    *(u32x4*)((char*)wB + HSWZ(off)) = v;
  }

  // L0 x-part weights: 8 frags = 32 VGPRs (small; compiler keeps these)
  bf16x8 wfx[8];
  if (ISL0) {
    const unsigned short* wrow = wl + (size_t)(wave * 512 + u0 + l15) * K;
#pragma unroll
    for (int kk = 0; kk < 8; ++kk) {
      wfx[kk] = *(const bf16x8*)(wrow + kk * 32 + kgrp * 8);
      asm volatile("" : "+v"(wfx[kk]));
    }
  }
  __syncthreads();  // wB ready

  // my wave's weight rows in wB: row = wave*16 + l15 (gate=wave, unit=l15)
  const int wrow_lds = (wave * 16 + l15) * 1024;  // byte offset base
  const unsigned short* wrow0 = wl + (size_t)(wave * 512 + u0 + l15) * K;  // h0-part (L1 pre-poll)

  const int ue = 2 * (tid & 7);
  const int be = tid >> 3;
  const float bi0 = bias[0 * 512 + u0 + ue], bi1 = bias[0 * 512 + u0 + ue + 1];
  const float bf0 = bias[1 * 512 + u0 + ue], bf1 = bias[1 * 512 + u0 + ue + 1];
  const float bg0 = bias[2 * 512 + u0 + ue], bg1 = bias[2 * 512 + u0 + ue + 1];
  const float bo0 = bias[3 * 512 + u0 + ue], bo1 = bias[3 * 512 + u0 + ue + 1];
  float cc0 = 0.f, cc1 = 0.f;
  unsigned short* myring = ISL0 ? h0r : h1r;
  int* myslot = (ISL0 ? s0 : s1) + wid2 * SLOT_STRIDE;

  for (int t = 0; t < T_SEQ; ++t) {
    f32x4 acc0 = {0.f, 0.f, 0.f, 0.f}, acc1 = {0.f, 0.f, 0.f, 0.f};

    if (ISL0) {
      // x fragment prefetch (static data, issued before the poll)
      bf16x8 xf0[8], xf1[8];
      const unsigned short* xt = xb + (size_t)t * (32 * 256);
#pragma unroll
      for (int kk = 0; kk < 8; ++kk) {
        xf0[kk] = *(const bf16x8*)(xt + l15 * 256 + kk * 32 + kgrp * 8);
        xf1[kk] = *(const bf16x8*)(xt + (16 + l15) * 256 + kk * 32 + kgrp * 8);
      }
      // the real wait: peers' h0[t-1]; L1 progress = ring guard
      spin_flags(s0, t, s1, t - (RING - 1), sf, NEG_INF);

      // stage h0[t-1]; x-part MFMAs overlap the loads in flight
      const unsigned short* hprev = myring + (size_t)((t - 1) & (RING - 1)) * (32 * 512);
      u32x4 th[8];
#pragma unroll
      for (int k = 0; k < 8; ++k)
        th[k] = llc_load16((const char*)hprev + (size_t)(tid + k * 256) * 16);
#pragma unroll
      for (int kk = 0; kk < 8; ++kk) {
        acc0 = __builtin_amdgcn_mfma_f32_16x16x32_bf16(xf0[kk], wfx[kk], acc0, 0, 0, 0);
        acc1 = __builtin_amdgcn_mfma_f32_16x16x32_bf16(xf1[kk], wfx[kk], acc1, 0, 0, 0);
      }
      vmwait();
#pragma unroll
      for (int k = 0; k < 8; ++k) {
        int off = (tid + k * 256) * 16;
        *(u32x4*)((char*)hA + HSWZ(off)) = th[k];
      }
      __syncthreads();
      // critical MFMA loop: A from hA (LDS), B from wB (LDS) — zero L2 on path
#pragma unroll
      for (int kk = 0; kk < 16; ++kk) {
        int cb = (kk * 32 + kgrp * 8) * 2;
        bf16x8 bw = *(const bf16x8*)((const char*)wB + HSWZ(wrow_lds + cb));
        bf16x8 a0 = *(const bf16x8*)((const char*)hA + HSWZ(l15 * 1024 + cb));
        bf16x8 a1 = *(const bf16x8*)((const char*)hA + HSWZ((16 + l15) * 1024 + cb));
        acc0 = __builtin_amdgcn_mfma_f32_16x16x32_bf16(a0, bw, acc0, 0, 0, 0);
        acc1 = __builtin_amdgcn_mfma_f32_16x16x32_bf16(a1, bw, acc1, 0, 0, 0);
      }
    } else {
      // ---- pre-poll phase: everything touching h0[t] (L0 runs ahead) ----
      spin_flags(s0, t + 1, s1, NEG_INF, sf, NEG_INF);
      const unsigned short* h0cur = h0r + (size_t)(t & (RING - 1)) * (32 * 512);
      u32x4 tx[8];
#pragma unroll
      for (int k = 0; k < 8; ++k)
        tx[k] = llc_load16((const char*)h0cur + (size_t)(tid + k * 256) * 16);
      vmwait();
#pragma unroll
      for (int k = 0; k < 8; ++k) {
        int off = (tid + k * 256) * 16;
        *(u32x4*)((char*)xA + HSWZ(off)) = tx[k];
      }
      __syncthreads();  // xA published
      // h0-part MFMAs with streamed weights — fully off the critical path
#pragma unroll
      for (int kk = 0; kk < 16; ++kk) {
        bf16x8 bw = *(const bf16x8*)(wrow0 + kk * 32 + kgrp * 8);
        int cb = (kk * 32 + kgrp * 8) * 2;
        bf16x8 a0 = *(const bf16x8*)((const char*)xA + HSWZ(l15 * 1024 + cb));
        bf16x8 a1 = *(const bf16x8*)((const char*)xA + HSWZ((16 + l15) * 1024 + cb));
        acc0 = __builtin_amdgcn_mfma_f32_16x16x32_bf16(a0, bw, acc0, 0, 0, 0);
        acc1 = __builtin_amdgcn_mfma_f32_16x16x32_bf16(a1, bw, acc1, 0, 0, 0);
      }

      // ---- critical phase: peers' h1[t-1] (+ FC ring guard) ----
      spin_flags(s0, NEG_INF, s1, t, sf, t - (RING - 1));
      const unsigned short* hprev = myring + (size_t)((t - 1) & (RING - 1)) * (32 * 512);
      u32x4 th[8];
#pragma unroll
      for (int k = 0; k < 8; ++k)
        th[k] = llc_load16((const char*)hprev + (size_t)(tid + k * 256) * 16);
      vmwait();
#pragma unroll
      for (int k = 0; k < 8; ++k) {
        int off = (tid + k * 256) * 16;
        *(u32x4*)((char*)hA + HSWZ(off)) = th[k];
      }
      __syncthreads();
      // critical MFMA loop: A from hA (LDS), B from wB (LDS)
#pragma unroll
      for (int kk = 0; kk < 16; ++kk) {
        int cb = (kk * 32 + kgrp * 8) * 2;
        bf16x8 bw = *(const bf16x8*)((const char*)wB + HSWZ(wrow_lds + cb));
        bf16x8 a0 = *(const bf16x8*)((const char*)hA + HSWZ(l15 * 1024 + cb));
        bf16x8 a1 = *(const bf16x8*)((const char*)hA + HSWZ((16 + l15) * 1024 + cb));
        acc0 = __builtin_amdgcn_mfma_f32_16x16x32_bf16(a0, bw, acc0, 0, 0, 0);
        acc1 = __builtin_amdgcn_mfma_f32_16x16x32_bf16(a1, bw, acc1, 0, 0, 0);
      }
    }

    // C/D: col(l15)=unit, row(kgrp*4+j)=batch.  gates[gate][batch][unit]
#pragma unroll
    for (int j = 0; j < 4; ++j) {
      gates[wave][kgrp * 4 + j][l15] = acc0[j];
      gates[wave][16 + kgrp * 4 + j][l15] = acc1[j];
    }
    __syncthreads();

    // ---- epilogue: 2 units x 1 batch per thread; c stays in registers ----
    unsigned short* hdst = myring + (size_t)(t & (RING - 1)) * (32 * 512);
    float i0 = sigm(gates[0][be][ue] + bi0);
    float ff0 = sigm(gates[1][be][ue] + bf0);
    float g0 = tanh_f(gates[2][be][ue] + bg0);
    float o0 = sigm(gates[3][be][ue] + bo0);
    cc0 = ff0 * cc0 + i0 * g0;
    float hv0 = o0 * tanh_f(cc0);
    float i1 = sigm(gates[0][be][ue + 1] + bi1);
    float ff1 = sigm(gates[1][be][ue + 1] + bf1);
    float g1 = tanh_f(gates[2][be][ue + 1] + bg1);
    float o1 = sigm(gates[3][be][ue + 1] + bo1);
    cc1 = ff1 * cc1 + i1 * g1;
    float hv1 = o1 * tanh_f(cc1);
    unsigned pv = (unsigned)f2b(hv0) | ((unsigned)f2b(hv1) << 16);
    llc_store4(hdst + (size_t)be * 512 + u0 + ue, pv);
    vmwait();            // drain BEFORE flag (r11 lesson)
    __syncthreads();
    if (tid == 0) flag_st(myslot, t + 1);
  }
}

// ---------------- main persistent pipelined kernel ----------------
__global__ void __launch_bounds__(256) lstm_main(
    const unsigned short* __restrict__ xb,
    const unsigned short* __restrict__ wl0,
    const unsigned short* __restrict__ wl1,
    const unsigned short* __restrict__ wfcp,
    const float* __restrict__ b0,
    const float* __restrict__ b1,
    const float* __restrict__ bfc,
    unsigned short* __restrict__ h0r,
    unsigned short* __restrict__ h1r,
    int* flags,
    float* __restrict__ out) {
  __shared__ __align__(16) unsigned short hA[32 * 512];
  __shared__ __align__(16) unsigned short xA[32 * 512];
  __shared__ __align__(16) unsigned short wB[64 * 512];
  __shared__ __align__(16) float gates[4][32][18];
  const int tid = threadIdx.x;
  const int wave = tid >> 6, lane = tid & 63, l15 = lane & 15, kgrp = lane >> 4;
  const int wid = blockIdx.x;
  int* s0 = flags;
  int* s1 = flags + NL0 * SLOT_STRIDE;
  int* sf = flags + (NL0 + NL1) * SLOT_STRIDE;

  if (wid < NL0) {
    lstm_path<1>(xb, wl0, b0, h0r, h1r, s0, s1, sf, wid, hA, xA, wB, gates);
  } else if (wid < NL0 + NL1) {
    lstm_path<0>(xb, wl1, b1, h0r, h1r, s0, s1, sf, wid - NL0, hA, xA, wB, gates);
  } else {
    const int fcw = wid - NL0 - NL1;  // 0..7
    const int mt = wave >> 1, ntile = wave & 1;
    const int orow = fcw * 32 + ntile * 16 + l15;
    bf16x8 wff[16];
#pragma unroll
    for (int kk = 0; kk < 16; ++kk)
      wff[kk] = *(const bf16x8*)(wfcp + (size_t)orow * 512 + kk * 32 + kgrp * 8);
    const float bb = bfc[orow];
    for (int t = 0; t < T_SEQ; ++t) {
      spin_flags(s0, NEG_INF, s1, t + 1, sf, NEG_INF);
      const unsigned short* hcur = h1r + (size_t)(t & (RING - 1)) * (32 * 512);
      unsigned short* buf = (t & 1) ? xA : hA;  // double buffer: safe LDS reuse
      u32x4 th[8];
#pragma unroll
      for (int k = 0; k < 8; ++k)
        th[k] = llc_load16((const char*)hcur + (size_t)(tid + k * 256) * 16);
      vmwait();
#pragma unroll
      for (int k = 0; k < 8; ++k) {
        int off = (tid + k * 256) * 16;
        *(u32x4*)((char*)buf + HSWZ(off)) = th[k];
      }
      __syncthreads();
      if (tid == 0) flag_st(sf + fcw * SLOT_STRIDE, t + 1);  // h1[t] consumed
      f32x4 acc = {0.f, 0.f, 0.f, 0.f};
#pragma unroll
      for (int kk = 0; kk < 16; ++kk) {
        int row = mt * 16 + l15;
        bf16x8 a = *(const bf16x8*)((const char*)buf + HSWZ(row * 1024 + (kk * 32 + kgrp * 8) * 2));
        acc = __builtin_amdgcn_mfma_f32_16x16x32_bf16(a, wff[kk], acc, 0, 0, 0);
      }
#pragma unroll
      for (int j = 0; j < 4; ++j) {
        int b = mt * 16 + kgrp * 4 + j;
        out[((size_t)b * T_SEQ + t) * 256 + orow] = acc[j] + bb;
      }
    }
  }
}

extern "C" void kernel_launch(void* const* d_in, const int* in_sizes, int n_in,
                              void* d_out, int out_size, void* d_ws, size_t ws_size,
                              hipStream_t stream) {
  const float* x    = (const float*)d_in[0];
  const float* wih0 = (const float*)d_in[1];
  const float* whh0 = (const float*)d_in[2];
  const float* b0   = (const float*)d_in[3];
  const float* wih1 = (const float*)d_in[4];
  const float* whh1 = (const float*)d_in[5];
  const float* b1   = (const float*)d_in[6];
  const float* wfc  = (const float*)d_in[7];
  const float* bfc  = (const float*)d_in[8];
  float* outp = (float*)d_out;

  char* ws = (char*)d_ws;
  size_t off = 0;
  unsigned short* wl0p = (unsigned short*)(ws + off); off += (size_t)2048 * 768 * 2;
  unsigned short* wl1p = (unsigned short*)(ws + off); off += (size_t)2048 * 1024 * 2;
  unsigned short* wfcp = (unsigned short*)(ws + off); off += (size_t)256 * 512 * 2;
  unsigned short* xbp  = (unsigned short*)(ws + off); off += (size_t)2048 * 32 * 256 * 2;
  unsigned short* h0rp = (unsigned short*)(ws + off); off += (size_t)RING * 32 * 512 * 2;
  unsigned short* h1rp = (unsigned short*)(ws + off); off += (size_t)RING * 32 * 512 * 2;
  int* flagsp = (int*)(ws + off); off += (size_t)NWG * SLOT_STRIDE * sizeof(int);

  lstm_prologue<<<dim3(1024), dim3(256), 0, stream>>>(
      x, wih0, whh0, wih1, whh1, wfc, wl0p, wl1p, wfcp, xbp, h0rp, h1rp, flagsp);

  lstm_main<<<dim3(NWG), dim3(256), 0, stream>>>(
      xbp, wl0p, wl1p, wfcp, b0, b1, bfc, h0rp, h1rp, flagsp, outp);
}